// Round 6
// baseline (78.831 us; speedup 1.0000x reference)
//
#include <hip/hip_runtime.h>

#define N2 (768 * 768)
#define NH 32

// Coarsened single-pass segmented reduce over sorted-key COO entries.
// Each thread vector-loads 4 consecutive (pair,node,coeff); intra-thread run
// boundaries flush 5 atomics directly; the thread's last-run partial goes
// through a 6-step wave segmented scan (keys sorted -> conditional merge is
// exact); scan run-tails flush 5 atomics. Atomics merge runs spanning
// thread/wave boundaries. Padding (coeff==0,pair==0) contributes zeros and is
// dropped by the v0>0 guard; all-padding waves exit after the coeff load.
__global__ __launch_bounds__(256) void scan_kernel(
    const int4* __restrict__ pair4, const int4* __restrict__ node4,
    const float4* __restrict__ coeff4, const float* __restrict__ ea,
    float* __restrict__ acc, int M4)
{
    int t = blockIdx.x * blockDim.x + threadIdx.x;
    int lane = threadIdx.x & 63;
    float4 c = (t < M4) ? coeff4[t] : make_float4(0.f, 0.f, 0.f, 0.f);
    bool any = (c.x != 0.f) || (c.y != 0.f) || (c.z != 0.f) || (c.w != 0.f);
    if (__ballot(any) == 0ULL) return;          // pure padding region
    int4  pk = (t < M4) ? pair4[t] : make_int4(-1, -1, -1, -1);
    int4  nd = (t < M4) ? node4[t] : make_int4(0, 0, 0, 0);

    float v0, v1, v2, v3, v4;
    int curkey = pk.x;
    {
        const float4 e = *reinterpret_cast<const float4*>(ea + nd.x * 4);
        v0 = c.x; v1 = c.x * e.x; v2 = c.x * e.y; v3 = c.x * e.z; v4 = c.x * e.w;
    }
#define STEP(KEY, ND, CC)                                                     \
    if ((KEY) != curkey) {                                                    \
        if (v0 > 0.f) {                                                       \
            atomicAdd(acc + curkey, v0);                                      \
            atomicAdd(acc + (size_t)N2 + curkey, v1);                         \
            atomicAdd(acc + (size_t)2 * N2 + curkey, v2);                     \
            atomicAdd(acc + (size_t)3 * N2 + curkey, v3);                     \
            atomicAdd(acc + (size_t)4 * N2 + curkey, v4);                     \
        }                                                                     \
        v0 = v1 = v2 = v3 = v4 = 0.f; curkey = (KEY);                         \
    }                                                                         \
    {                                                                         \
        const float4 e = *reinterpret_cast<const float4*>(ea + (ND) * 4);     \
        v0 += (CC); v1 += (CC) * e.x; v2 += (CC) * e.y;                       \
        v3 += (CC) * e.z; v4 += (CC) * e.w;                                   \
    }
    STEP(pk.y, nd.y, c.y)
    STEP(pk.z, nd.z, c.z)
    STEP(pk.w, nd.w, c.w)
#undef STEP

#pragma unroll
    for (int d = 1; d < 64; d <<= 1) {
        int   ku = __shfl_up(curkey, d);
        float t0 = __shfl_up(v0, d), t1 = __shfl_up(v1, d), t2 = __shfl_up(v2, d),
              t3 = __shfl_up(v3, d), t4 = __shfl_up(v4, d);
        if (lane >= d && ku == curkey) { v0 += t0; v1 += t1; v2 += t2; v3 += t3; v4 += t4; }
    }
    int kdn = __shfl_down(curkey, 1);
    bool lastl = (lane == 63) || (kdn != curkey);
    if (lastl && v0 > 0.f) {
        atomicAdd(acc + curkey, v0);
        atomicAdd(acc + (size_t)N2 + curkey, v1);
        atomicAdd(acc + (size_t)2 * N2 + curkey, v2);
        atomicAdd(acc + (size_t)3 * N2 + curkey, v3);
        atomicAdd(acc + (size_t)4 * N2 + curkey, v4);
    }
}

// Defensive tail for M % 4 != 0 (M is 10M in practice, so normally unused).
__global__ void tail_kernel(const int* __restrict__ pair, const int* __restrict__ node,
                            const float* __restrict__ coeff, const float* __restrict__ ea,
                            float* __restrict__ acc, int start, int M)
{
    int e = start + blockIdx.x * blockDim.x + threadIdx.x;
    if (e >= M) return;
    float cc = coeff[e];
    if (cc == 0.f) return;
    int key = pair[e];
    const float4 v = *reinterpret_cast<const float4*>(ea + node[e] * 4);
    atomicAdd(acc + key, cc);
    atomicAdd(acc + (size_t)N2 + key, cc * v.x);
    atomicAdd(acc + (size_t)2 * N2 + key, cc * v.y);
    atomicAdd(acc + (size_t)3 * N2 + key, cc * v.z);
    atomicAdd(acc + (size_t)4 * N2 + key, cc * v.w);
}

// out[h,p] = b[h]*a0[p] + sum_k W[h][k]*a{k+1}[p], float4-vectorized:
// each thread handles 4 consecutive pairs; coalesced 1KB-per-instruction
// loads and stores. Every output element written exactly once.
__global__ __launch_bounds__(256) void expand_kernel(
    const float* __restrict__ acc, const float* __restrict__ W,
    const float* __restrict__ b, float* __restrict__ out)
{
    __shared__ float sW[NH * 4];
    __shared__ float sB[NH];
    int t = threadIdx.x;
    if (t < NH * 4) sW[t] = W[t];
    if (t < NH) sB[t] = b[t];
    __syncthreads();
    size_t p4 = ((size_t)blockIdx.x * 256 + t) * 4;   // N2 = 576 * 1024
    const float4 a0 = *reinterpret_cast<const float4*>(acc + p4);
    const float4 a1 = *reinterpret_cast<const float4*>(acc + (size_t)N2 + p4);
    const float4 a2 = *reinterpret_cast<const float4*>(acc + (size_t)2 * N2 + p4);
    const float4 a3 = *reinterpret_cast<const float4*>(acc + (size_t)3 * N2 + p4);
    const float4 a4 = *reinterpret_cast<const float4*>(acc + (size_t)4 * N2 + p4);
#pragma unroll
    for (int h = 0; h < NH; ++h) {
        float bb = sB[h], w0 = sW[h * 4], w1 = sW[h * 4 + 1],
              w2 = sW[h * 4 + 2], w3 = sW[h * 4 + 3];
        float4 o;
        o.x = bb * a0.x + w0 * a1.x + w1 * a2.x + w2 * a3.x + w3 * a4.x;
        o.y = bb * a0.y + w0 * a1.y + w1 * a2.y + w2 * a3.y + w3 * a4.y;
        o.z = bb * a0.z + w0 * a1.z + w1 * a2.z + w2 * a3.z + w3 * a4.z;
        o.w = bb * a0.w + w0 * a1.w + w1 * a2.w + w2 * a3.w + w3 * a4.w;
        *reinterpret_cast<float4*>(out + (size_t)h * N2 + p4) = o;
    }
}

extern "C" void kernel_launch(void* const* d_in, const int* in_sizes, int n_in,
                              void* d_out, int out_size, void* d_ws, size_t ws_size,
                              hipStream_t stream) {
    // inputs: 0=x 1=edge_attr 2=W 3=b 4=edge_idx 5=pair_idx 6=node_idx 7=coeff 8=num_nodes
    const float* ea    = (const float*)d_in[1];
    const float* W     = (const float*)d_in[2];
    const float* b     = (const float*)d_in[3];
    const int*   pair  = (const int*)d_in[5];
    const int*   node  = (const int*)d_in[6];
    const float* coeff = (const float*)d_in[7];
    float* out = (float*)d_out;
    int M = in_sizes[5];

    float* acc = (float*)d_ws;   // 5 planes of N2 floats = 11.8 MB

    hipMemsetAsync(acc, 0, (size_t)5 * N2 * sizeof(float), stream);

    int M4 = M >> 2;
    int rem = M - (M4 << 2);
    scan_kernel<<<(M4 + 255) / 256, 256, 0, stream>>>(
        (const int4*)pair, (const int4*)node, (const float4*)coeff, ea, acc, M4);
    if (rem > 0)
        tail_kernel<<<1, 64, 0, stream>>>(pair, node, coeff, ea, acc, M4 << 2, M);

    expand_kernel<<<N2 / 1024, 256, 0, stream>>>(acc, W, b, out);
}

// Round 7
// 57.781 us; speedup vs baseline: 1.3643x; 1.3643x over previous
//
#include <hip/hip_runtime.h>

#define N2 (768 * 768)
#define NH 32
#define PPB 256      // pairs per chunk (== threads per block)
#define CHUNKS 3     // chunks per block; 768 blocks * 768 pairs = N2 exactly
#define CAP 6144     // staged entries per chunk (48 KB LDS); fallback beyond

// out[h,p] = b[h]*S0[p] + sum_k W[h][k]*S[k][p], where S0 = sum_e c_e and
// S[k] = sum_e c_e * ea[node_e][k] over pair p's entry segment.
// pair_idx is sorted ascending over the valid prefix; padding has coeff==0,
// so key(e) = (coeff==0 ? INT_MAX : pair[e]) is globally sorted -> per-block
// batched binary searches give chunk entry ranges. Entries staged coalesced
// into LDS with run boundaries marked in-flight; each thread walks its own
// pair from LDS; 32-channel expansion fused; every output written exactly
// once (missing pairs get ps=pe=0 -> exact zero, matching segment_sum).
__global__ __launch_bounds__(256) void fused_kernel(
    const int* __restrict__ pair, const int* __restrict__ node,
    const float* __restrict__ coeff, const float* __restrict__ ea,
    const float* __restrict__ W, const float* __restrict__ b,
    float* __restrict__ out, int M)
{
    __shared__ float2 ent[CAP];          // (coeff, node bits)
    __shared__ int ps[PPB], pe[PPB];
    __shared__ int sBnd[CHUNKS + 1];
    __shared__ float sW[NH * 4];
    __shared__ float sBias[NH];

    const int t = threadIdx.x;
    const int pbase = blockIdx.x * (PPB * CHUNKS);

    if (t < NH * 4) sW[t] = W[t];
    if (t < NH) sBias[t] = b[t];

    // Batched lower_bound: first e with key(e) >= target. 4 lanes search the
    // 4 chunk boundaries concurrently -> one ~24-probe latency for all.
    if (t <= CHUNKS) {
        int target = pbase + t * PPB;
        int lo = 0, hi = M;
        while (lo < hi) {
            int mid = (lo + hi) >> 1;
            int key = (coeff[mid] == 0.f) ? 0x7fffffff : pair[mid];
            if (key < target) lo = mid + 1; else hi = mid;
        }
        sBnd[t] = lo;
    }

    for (int c = 0; c < CHUNKS; ++c) {
        __syncthreads();                 // bounds ready / prev chunk consumed
        ps[t] = 0; pe[t] = 0;
        __syncthreads();
        const int p0 = pbase + c * PPB;
        const int s0 = sBnd[c], s1 = sBnd[c + 1];
        const int cnt = s1 - s0;         // block-uniform
        float a0 = 0.f, a1 = 0.f, a2 = 0.f, a3 = 0.f, a4 = 0.f;

        if (cnt <= CAP) {
            // coalesced stage + in-flight run-boundary detection
            for (int i = t; i < cnt; i += PPB) {
                int e = s0 + i;
                float cc = coeff[e];
                int nd = node[e];
                ent[i] = make_float2(cc, __int_as_float(nd));
                int pp = pair[e];
                if (i == 0 || pair[e - 1] != pp) ps[pp - p0] = i;
                if (i == cnt - 1 || pair[e + 1] != pp) pe[pp - p0] = i + 1;
            }
            __syncthreads();
            // thread t owns pair p0+t: serial walk from LDS, ea is L1-hot
            const int s = ps[t], e = pe[t];
            for (int k = s; k < e; ++k) {
                float2 en = ent[k];
                float cc = en.x;
                int nd = __float_as_int(en.y);
                const float4 v = *reinterpret_cast<const float4*>(ea + nd * 4);
                a0 += cc;
                a1 += cc * v.x; a2 += cc * v.y; a3 += cc * v.z; a4 += cc * v.w;
            }
        } else {
            // rare overflow: per-thread bounds via binary search, walk global
            __syncthreads();
            const int tgt = p0 + t;
            int lo = s0, hi = s1;
            while (lo < hi) { int mid = (lo + hi) >> 1; if (pair[mid] < tgt) lo = mid + 1; else hi = mid; }
            const int s = lo; hi = s1;
            while (lo < hi) { int mid = (lo + hi) >> 1; if (pair[mid] <= tgt) lo = mid + 1; else hi = mid; }
            for (int k = s; k < lo; ++k) {
                float cc = coeff[k];
                const float4 v = *reinterpret_cast<const float4*>(ea + node[k] * 4);
                a0 += cc;
                a1 += cc * v.x; a2 += cc * v.y; a3 += cc * v.z; a4 += cc * v.w;
            }
        }

        // fused 32-channel expansion; 256B/wave coalesced stores
        const size_t op = (size_t)p0 + t;
#pragma unroll
        for (int h = 0; h < NH; ++h) {
            out[(size_t)h * N2 + op] =
                sBias[h] * a0 + sW[h * 4 + 0] * a1 + sW[h * 4 + 1] * a2
              + sW[h * 4 + 2] * a3 + sW[h * 4 + 3] * a4;
        }
    }
}

extern "C" void kernel_launch(void* const* d_in, const int* in_sizes, int n_in,
                              void* d_out, int out_size, void* d_ws, size_t ws_size,
                              hipStream_t stream) {
    // inputs: 0=x 1=edge_attr 2=W 3=b 4=edge_idx 5=pair_idx 6=node_idx 7=coeff 8=num_nodes
    const float* ea    = (const float*)d_in[1];
    const float* W     = (const float*)d_in[2];
    const float* b     = (const float*)d_in[3];
    const int*   pair  = (const int*)d_in[5];
    const int*   node  = (const int*)d_in[6];
    const float* coeff = (const float*)d_in[7];
    float* out = (float*)d_out;
    int M = in_sizes[5];

    fused_kernel<<<N2 / (PPB * CHUNKS), PPB, 0, stream>>>(
        pair, node, coeff, ea, W, b, out, M);
}